// Round 4
// baseline (162.665 us; speedup 1.0000x reference)
//
#include <hip/hip_runtime.h>

// LimitedKVWithBBPM — round 4.
// r3 lesson: reduce is capped ~2.15 TB/s by outstanding-miss limit (MLP
// batching was a null). So cut BYTES and PASSES instead: bucket queries by
// slot, and scatter each slot's sum directly to its querying output rows.
// Eliminates acc (64 MB write + ~130 MB random re-read) and the whole gather
// pass; skips never-queried slots (~14% of vals/bbpm reads).

typedef float f32x4 __attribute__((ext_vector_type(4)));
typedef int   i32x4 __attribute__((ext_vector_type(4)));

constexpr int DIM    = 128;
constexpr int MEM    = 131072;   // 2^17 -> mask
constexpr int KCACHE = 8192;
constexpr int CAP    = 8;        // token bucket capacity (mean load 2)
constexpr int QCAP   = 8;        // query bucket capacity (mean load ~1.9)

__device__ __forceinline__ f32x4 nt_ldrow(const float* __restrict__ p, int q) {
    return __builtin_nontemporal_load(reinterpret_cast<const f32x4*>(p) + q);
}
__device__ __forceinline__ void nt_strow(float* __restrict__ p, int q, f32x4 v) {
    __builtin_nontemporal_store(v, reinterpret_cast<f32x4*>(p) + q);
}

// One thread per token: claim a bucket position in its slot.
__global__ void fill_kernel(const int* __restrict__ keys,
                            int* __restrict__ cnt, int* __restrict__ bucket,
                            int* __restrict__ ovf_cnt, int* __restrict__ ovf, int n) {
    int i = blockIdx.x * 256 + threadIdx.x;
    if (i >= n) return;
    int slot = ((unsigned)keys[i]) & (MEM - 1);
    int pos = atomicAdd(&cnt[slot], 1);
    if (pos < CAP) bucket[slot * CAP + pos] = i;
    else { int k = atomicAdd(ovf_cnt, 1); ovf[k] = i; }
}

// pos_table[positions[n-K+j]] = j
__global__ void build_pos_kernel(const int* __restrict__ positions,
                                 int* __restrict__ pos_table, int n, int K) {
    int j = blockIdx.x * 256 + threadIdx.x;
    if (j >= K) return;
    int p = positions[n - K + j];
    if (p >= 0 && p < n) pos_table[p] = j;
}

// One thread per query: hit -> hit list; miss -> query bucket by slot.
__global__ void qfill_kernel(const int* __restrict__ qkeys,
                             const int* __restrict__ qpos,
                             const int* __restrict__ pos_table,
                             int* __restrict__ qcnt, int* __restrict__ qbucket,
                             int* __restrict__ qovf_cnt, int* __restrict__ qovf,
                             int* __restrict__ hcnt, int* __restrict__ hlist_r,
                             int* __restrict__ hlist_i, int n) {
    int r = blockIdx.x * 256 + threadIdx.x;
    if (r >= n) return;
    int qp = qpos[r];
    int idx = (qp >= 0 && qp < n) ? pos_table[qp] : -1;
    if (idx >= 0) {
        int h = atomicAdd(hcnt, 1);
        hlist_r[h] = r; hlist_i[h] = idx;
    } else {
        int slot = ((unsigned)qkeys[r]) & (MEM - 1);
        int p = atomicAdd(&qcnt[slot], 1);
        if (p < QCAP) qbucket[slot * QCAP + p] = r;
        else { int k = atomicAdd(qovf_cnt, 1); qovf[k] = r; }
    }
}

// One 32-lane group per QUERIED slot: sum bbpm + bucket rows, then scatter
// the sum to every querying output row (full-line NT stores).
__global__ void reduce_scatter_kernel(const float* __restrict__ vals,
                                      const float* __restrict__ bbpm,
                                      const int* __restrict__ keys,
                                      const int* __restrict__ cnt,
                                      const int* __restrict__ bucket,
                                      const int* __restrict__ qcnt,
                                      const int* __restrict__ qbucket,
                                      const int* __restrict__ ovf_cnt,
                                      const int* __restrict__ ovf,
                                      float* __restrict__ out) {
    int s = blockIdx.x * 8 + (threadIdx.x >> 5);
    int q = threadIdx.x & 31;
    int nq = qcnt[s];
    if (nq == 0) return;                       // nobody asks for this slot

    int c = cnt[s];
    i32x4 b = *reinterpret_cast<const i32x4*>(bucket + s * CAP);
    int r0 = c > 0 ? b.x : 0, r1 = c > 1 ? b.y : 0;
    float m0 = c > 0 ? 1.f : 0.f, m1 = c > 1 ? 1.f : 0.f;

    f32x4 A  = nt_ldrow(bbpm + (size_t)s  * DIM, q);
    f32x4 V0 = nt_ldrow(vals + (size_t)r0 * DIM, q);
    f32x4 V1 = nt_ldrow(vals + (size_t)r1 * DIM, q);
    f32x4 a = A + m0 * V0 + m1 * V1;

    if (c > 2) {
        a += nt_ldrow(vals + (size_t)b.z * DIM, q);
        if (c > 3) {
            a += nt_ldrow(vals + (size_t)b.w * DIM, q);
            int cc = c < CAP ? c : CAP;
            for (int j = 4; j < cc; ++j)
                a += nt_ldrow(vals + (size_t)bucket[s * CAP + j] * DIM, q);
        }
    }
    if (c > CAP) {                              // pathological keys only
        int L = *ovf_cnt;
        for (int j = 0; j < L; ++j) {
            int i = ovf[j];
            if ((((unsigned)keys[i]) & (MEM - 1)) == (unsigned)s)
                a += nt_ldrow(vals + (size_t)i * DIM, q);
        }
    }

    int wq = nq < QCAP ? nq : QCAP;
    for (int t = 0; t < wq; ++t) {
        int r = qbucket[s * QCAP + t];
        nt_strow(out + (size_t)r * DIM, q, a);
    }
}

// Hit rows: out[r] = vals[base + idx]. 32 lanes per entry, grid-stride.
__global__ void hit_kernel(const float* __restrict__ vals,
                           const int* __restrict__ hcnt,
                           const int* __restrict__ hlist_r,
                           const int* __restrict__ hlist_i,
                           float* __restrict__ out, int base) {
    int total = *hcnt;
    int tid = blockIdx.x * 256 + threadIdx.x, stride = gridDim.x * 256;
    for (int w = tid; w < total * 32; w += stride) {
        int e = w >> 5, q = w & 31;
        f32x4 v = nt_ldrow(vals + (size_t)(base + hlist_i[e]) * DIM, q);
        nt_strow(out + (size_t)hlist_r[e] * DIM, q, v);
    }
}

// Query-overflow rows (qcnt > QCAP, rare): compute the slot sum directly.
__global__ void qovf_kernel(const float* __restrict__ vals,
                            const float* __restrict__ bbpm,
                            const int* __restrict__ keys,
                            const int* __restrict__ cnt,
                            const int* __restrict__ bucket,
                            const int* __restrict__ ovf_cnt,
                            const int* __restrict__ ovf,
                            const int* __restrict__ qkeys,
                            const int* __restrict__ qovf_cnt,
                            const int* __restrict__ qovf,
                            float* __restrict__ out) {
    int total = *qovf_cnt;
    int tid = blockIdx.x * 256 + threadIdx.x, stride = gridDim.x * 256;
    for (int w = tid; w < total * 32; w += stride) {
        int e = w >> 5, q = w & 31;
        int r = qovf[e];
        int s = ((unsigned)qkeys[r]) & (MEM - 1);
        int c = cnt[s], cc = c < CAP ? c : CAP;
        f32x4 a = nt_ldrow(bbpm + (size_t)s * DIM, q);
        for (int j = 0; j < cc; ++j)
            a += nt_ldrow(vals + (size_t)bucket[s * CAP + j] * DIM, q);
        if (c > CAP) {
            int L = *ovf_cnt;
            for (int j = 0; j < L; ++j) {
                int i = ovf[j];
                if ((((unsigned)keys[i]) & (MEM - 1)) == (unsigned)s)
                    a += nt_ldrow(vals + (size_t)i * DIM, q);
            }
        }
        nt_strow(out + (size_t)r * DIM, q, a);
    }
}

extern "C" void kernel_launch(void* const* d_in, const int* in_sizes, int n_in,
                              void* d_out, int out_size, void* d_ws, size_t ws_size,
                              hipStream_t stream) {
    const int*   keys      = (const int*)d_in[0];
    const float* vals      = (const float*)d_in[1];
    const int*   positions = (const int*)d_in[2];
    const int*   qkeys     = (const int*)d_in[3];
    const int*   qpos      = (const int*)d_in[4];
    const float* bbpm      = (const float*)d_in[5];
    float* out = (float*)d_out;

    const int n = in_sizes[0];                       // B*T tokens

    // d_ws layout (counters adjacent to cnt/qcnt for a single memset).
    char* ws = (char*)d_ws;
    int* cnt       = (int*)ws;                                   // 512 KiB
    int* qcnt      = cnt + MEM;                                  // 512 KiB
    int* ctrs      = qcnt + MEM;        // [0]=ovf_cnt [1]=qovf_cnt [2]=hcnt
    int* pos_table = ctrs + 64;                                  // n*4
    int* bucket    = pos_table + n;                              // MEM*CAP*4 = 4 MiB
    int* qbucket   = bucket + MEM * CAP;                         // 4 MiB
    int* ovf       = qbucket + MEM * QCAP;                       // n*4
    int* qovf      = ovf + n;                                    // n*4
    int* hlist_r   = qovf + n;                                   // n*4
    int* hlist_i   = hlist_r + n;                                // n*4

    hipMemsetAsync(cnt, 0, (size_t)(2 * MEM + 64) * 4, stream);
    hipMemsetAsync(pos_table, 0xFF, (size_t)n * 4, stream);

    fill_kernel<<<(n + 255) / 256, 256, 0, stream>>>(keys, cnt, bucket, &ctrs[0], ovf, n);
    build_pos_kernel<<<(KCACHE + 255) / 256, 256, 0, stream>>>(positions, pos_table, n, KCACHE);
    qfill_kernel<<<(n + 255) / 256, 256, 0, stream>>>(qkeys, qpos, pos_table,
                                                      qcnt, qbucket, &ctrs[1], qovf,
                                                      &ctrs[2], hlist_r, hlist_i, n);
    reduce_scatter_kernel<<<MEM / 8, 256, 0, stream>>>(vals, bbpm, keys, cnt, bucket,
                                                       qcnt, qbucket, &ctrs[0], ovf, out);
    hit_kernel<<<256, 256, 0, stream>>>(vals, &ctrs[2], hlist_r, hlist_i, out, n - KCACHE);
    qovf_kernel<<<64, 256, 0, stream>>>(vals, bbpm, keys, cnt, bucket, &ctrs[0], ovf,
                                        qkeys, &ctrs[1], qovf, out);
}

// Round 5
// 133.368 us; speedup vs baseline: 1.2197x; 1.2197x over previous
//
#include <hip/hip_runtime.h>

// LimitedKVWithBBPM — round 5.
// r4 lesson: random 512B out-writes kill DRAM page locality; reverted.
// r2/r3 lesson: reduce's limiter is random 512B *HBM* fetches of vals
// (gather does the same pattern from L3 at 9 TB/s). This round decouples:
// sequential prefetch of vals into L3, then reduce's random reads hit L3.
// Plus: skip never-queried slots (qflag), NT for read-once/write-once streams.

typedef float f32x4 __attribute__((ext_vector_type(4)));
typedef int   i32x4 __attribute__((ext_vector_type(4)));

constexpr int DIM    = 128;
constexpr int MEM    = 131072;   // 2^17 -> mask
constexpr int KCACHE = 8192;
constexpr int CAP    = 8;        // token bucket capacity (mean load 2)

__device__ __forceinline__ f32x4 ldrow(const float* __restrict__ p, int q) {
    return *reinterpret_cast<const f32x4*>(p + q * 4);
}
__device__ __forceinline__ f32x4 nt_ldrow(const float* __restrict__ p, int q) {
    return __builtin_nontemporal_load(reinterpret_cast<const f32x4*>(p) + q);
}
__device__ __forceinline__ void nt_strow(float* __restrict__ p, int q, f32x4 v) {
    __builtin_nontemporal_store(v, reinterpret_cast<f32x4*>(p) + q);
}

// One thread per token: claim a bucket position in its slot.
__global__ void fill_kernel(const int* __restrict__ keys,
                            int* __restrict__ cnt, int* __restrict__ bucket,
                            int* __restrict__ ovf_cnt, int* __restrict__ ovf, int n) {
    int i = blockIdx.x * 256 + threadIdx.x;
    if (i >= n) return;
    int slot = ((unsigned)keys[i]) & (MEM - 1);
    int pos = atomicAdd(&cnt[slot], 1);
    if (pos < CAP) bucket[slot * CAP + pos] = i;
    else { int k = atomicAdd(ovf_cnt, 1); ovf[k] = i; }
}

// pos_table[positions[n-K+j]] = j
__global__ void build_pos_kernel(const int* __restrict__ positions,
                                 int* __restrict__ pos_table, int n, int K) {
    int j = blockIdx.x * 256 + threadIdx.x;
    if (j >= K) return;
    int p = positions[n - K + j];
    if (p >= 0 && p < n) pos_table[p] = j;
}

// Mark slots that at least one missing query needs (benign racy store of 1).
__global__ void qfill_kernel(const int* __restrict__ qkeys,
                             const int* __restrict__ qpos,
                             const int* __restrict__ pos_table,
                             int* __restrict__ qflag, int n) {
    int r = blockIdx.x * 256 + threadIdx.x;
    if (r >= n) return;
    int qp = qpos[r];
    int idx = (qp >= 0 && qp < n) ? pos_table[qp] : -1;
    if (idx < 0) qflag[((unsigned)qkeys[r]) & (MEM - 1)] = 1;
}

// Sequential streaming read of vals -> allocates the 134 MB into L3 so the
// following reduce's random row reads hit L3 instead of HBM (random 512B HBM
// fetch measured ~1 TB/s; L3 random reads ~9 TB/s in r3's gather).
__global__ void prefetch_kernel(const f32x4* __restrict__ v4, int n4) {
    int tid = blockIdx.x * 256 + threadIdx.x;
    int stride = gridDim.x * 256;
    float s = 0.f;
    for (int t = tid; t < n4; t += stride) {
        f32x4 v = v4[t];
        s += v.x + v.y + v.z + v.w;
    }
    asm volatile("" :: "v"(s));   // keep loads live (rule #17), no output
}

// One 32-lane group per 2 slots; skip unqueried slots; acc write sequential.
__global__ void reduce_kernel(const float* __restrict__ vals,
                              const float* __restrict__ bbpm,
                              const int* __restrict__ cnt,
                              const int* __restrict__ qflag,
                              const int* __restrict__ bucket,
                              float* __restrict__ acc) {
    int g = threadIdx.x >> 5;
    int q = threadIdx.x & 31;
    int s0 = blockIdx.x * 16 + g;
    int s1 = s0 + 8;

    int f0 = qflag[s0], f1 = qflag[s1];
    if ((f0 | f1) == 0) return;          // group-uniform: no query needs these

    int c0 = f0 ? cnt[s0] : 0; if (c0 > CAP) c0 = CAP;
    int c1 = f1 ? cnt[s1] : 0; if (c1 > CAP) c1 = CAP;
    i32x4 b0 = *reinterpret_cast<const i32x4*>(bucket + s0 * CAP);
    i32x4 b1 = *reinterpret_cast<const i32x4*>(bucket + s1 * CAP);

    int r00 = c0 > 0 ? b0.x : 0, r01 = c0 > 1 ? b0.y : 0;
    int r10 = c1 > 0 ? b1.x : 0, r11 = c1 > 1 ? b1.y : 0;
    float m00 = c0 > 0 ? 1.f : 0.f, m01 = c0 > 1 ? 1.f : 0.f;
    float m10 = c1 > 0 ? 1.f : 0.f, m11 = c1 > 1 ? 1.f : 0.f;

    // bbpm is read-once: NT keeps it from evicting vals/acc in L3.
    const float* bb0 = bbpm + (f0 ? (size_t)s0 * DIM : 0);
    const float* bb1 = bbpm + (f1 ? (size_t)s1 * DIM : 0);
    f32x4 A0  = nt_ldrow(bb0, q);
    f32x4 A1  = nt_ldrow(bb1, q);
    f32x4 V00 = ldrow(vals + (size_t)r00 * DIM, q);
    f32x4 V01 = ldrow(vals + (size_t)r01 * DIM, q);
    f32x4 V10 = ldrow(vals + (size_t)r10 * DIM, q);
    f32x4 V11 = ldrow(vals + (size_t)r11 * DIM, q);

    f32x4 a0 = A0 + m00 * V00 + m01 * V01;
    f32x4 a1 = A1 + m10 * V10 + m11 * V11;

    if (c0 > 2) {
        a0 += ldrow(vals + (size_t)b0.z * DIM, q);
        if (c0 > 3) {
            a0 += ldrow(vals + (size_t)b0.w * DIM, q);
            for (int j = 4; j < c0; ++j)
                a0 += ldrow(vals + (size_t)bucket[s0 * CAP + j] * DIM, q);
        }
    }
    if (c1 > 2) {
        a1 += ldrow(vals + (size_t)b1.z * DIM, q);
        if (c1 > 3) {
            a1 += ldrow(vals + (size_t)b1.w * DIM, q);
            for (int j = 4; j < c1; ++j)
                a1 += ldrow(vals + (size_t)bucket[s1 * CAP + j] * DIM, q);
        }
    }

    if (f0) *reinterpret_cast<f32x4*>(acc + (size_t)s0 * DIM + q * 4) = a0;
    if (f1) *reinterpret_cast<f32x4*>(acc + (size_t)s1 * DIM + q * 4) = a1;
}

// Rare path: tokens beyond CAP get atomic-added (expected ~0 for these keys).
__global__ void overflow_kernel(const float* __restrict__ vals,
                                const int* __restrict__ keys,
                                const int* __restrict__ ovf_cnt,
                                const int* __restrict__ ovf,
                                float* __restrict__ acc) {
    int total = *ovf_cnt;
    int tid = blockIdx.x * 256 + threadIdx.x, stride = gridDim.x * 256;
    for (int w = tid; w < total * 32; w += stride) {
        int e = w >> 5, q = w & 31;
        int i = ovf[e];
        int slot = ((unsigned)keys[i]) & (MEM - 1);
        f32x4 v = ldrow(vals + (size_t)i * DIM, q);
        float* dst = acc + (size_t)slot * DIM + q * 4;
        atomicAdd(dst + 0, v.x);
        atomicAdd(dst + 1, v.y);
        atomicAdd(dst + 2, v.z);
        atomicAdd(dst + 3, v.w);
    }
}

// 4 output rows per 32-lane group; sequential NT out writes.
__global__ void gather_kernel(const float* __restrict__ vals,
                              const float* __restrict__ acc,
                              const int* __restrict__ qkeys,
                              const int* __restrict__ qpos,
                              const int* __restrict__ pos_table,
                              float* __restrict__ out, int n, int base) {
    int g = threadIdx.x >> 5;
    int q = threadIdx.x & 31;
    int r0 = blockIdx.x * 32 + g;
    int r1 = r0 + 8, r2 = r0 + 16, r3 = r0 + 24;

    bool k0 = r0 < n, k1 = r1 < n, k2 = r2 < n, k3 = r3 < n;
    int qp0 = k0 ? qpos[r0] : -1, qp1 = k1 ? qpos[r1] : -1;
    int qp2 = k2 ? qpos[r2] : -1, qp3 = k3 ? qpos[r3] : -1;
    int qk0 = k0 ? qkeys[r0] : 0, qk1 = k1 ? qkeys[r1] : 0;
    int qk2 = k2 ? qkeys[r2] : 0, qk3 = k3 ? qkeys[r3] : 0;

    int i0 = (qp0 >= 0 && qp0 < n) ? pos_table[qp0] : -1;
    int i1 = (qp1 >= 0 && qp1 < n) ? pos_table[qp1] : -1;
    int i2 = (qp2 >= 0 && qp2 < n) ? pos_table[qp2] : -1;
    int i3 = (qp3 >= 0 && qp3 < n) ? pos_table[qp3] : -1;

    const float* s0 = (i0 >= 0) ? vals + (size_t)(base + i0) * DIM
                                : acc + (size_t)(((unsigned)qk0) & (MEM - 1)) * DIM;
    const float* s1 = (i1 >= 0) ? vals + (size_t)(base + i1) * DIM
                                : acc + (size_t)(((unsigned)qk1) & (MEM - 1)) * DIM;
    const float* s2 = (i2 >= 0) ? vals + (size_t)(base + i2) * DIM
                                : acc + (size_t)(((unsigned)qk2) & (MEM - 1)) * DIM;
    const float* s3 = (i3 >= 0) ? vals + (size_t)(base + i3) * DIM
                                : acc + (size_t)(((unsigned)qk3) & (MEM - 1)) * DIM;

    f32x4 v0 = ldrow(s0, q);
    f32x4 v1 = ldrow(s1, q);
    f32x4 v2 = ldrow(s2, q);
    f32x4 v3 = ldrow(s3, q);

    if (k0) nt_strow(out + (size_t)r0 * DIM, q, v0);
    if (k1) nt_strow(out + (size_t)r1 * DIM, q, v1);
    if (k2) nt_strow(out + (size_t)r2 * DIM, q, v2);
    if (k3) nt_strow(out + (size_t)r3 * DIM, q, v3);
}

extern "C" void kernel_launch(void* const* d_in, const int* in_sizes, int n_in,
                              void* d_out, int out_size, void* d_ws, size_t ws_size,
                              hipStream_t stream) {
    const int*   keys      = (const int*)d_in[0];
    const float* vals      = (const float*)d_in[1];
    const int*   positions = (const int*)d_in[2];
    const int*   qkeys     = (const int*)d_in[3];
    const int*   qpos      = (const int*)d_in[4];
    const float* bbpm      = (const float*)d_in[5];
    float* out = (float*)d_out;

    const int n = in_sizes[0];                  // B*T tokens

    char* ws = (char*)d_ws;
    int*   cnt       = (int*)ws;                       // MEM
    int*   qflag     = cnt + MEM;                      // MEM
    int*   ctrs      = qflag + MEM;                    // 64  ([0]=ovf_cnt)
    int*   pos_table = ctrs + 64;                      // n
    int*   bucket    = pos_table + n;                  // MEM*CAP (4 MiB)
    int*   ovf       = bucket + MEM * CAP;             // n
    float* acc       = (float*)(ovf + n);              // MEM*DIM (64 MiB), 16B-aligned

    hipMemsetAsync(cnt, 0, (size_t)(2 * MEM + 64) * 4, stream);
    hipMemsetAsync(pos_table, 0xFF, (size_t)n * 4, stream);

    fill_kernel<<<(n + 255) / 256, 256, 0, stream>>>(keys, cnt, bucket, &ctrs[0], ovf, n);
    build_pos_kernel<<<(KCACHE + 255) / 256, 256, 0, stream>>>(positions, pos_table, n, KCACHE);
    qfill_kernel<<<(n + 255) / 256, 256, 0, stream>>>(qkeys, qpos, pos_table, qflag, n);
    prefetch_kernel<<<2048, 256, 0, stream>>>((const f32x4*)vals, n * (DIM / 4));
    reduce_kernel<<<MEM / 16, 256, 0, stream>>>(vals, bbpm, cnt, qflag, bucket, acc);
    overflow_kernel<<<64, 256, 0, stream>>>(vals, keys, &ctrs[0], ovf, acc);
    gather_kernel<<<(n + 31) / 32, 256, 0, stream>>>(vals, acc, qkeys, qpos, pos_table,
                                                     out, n, n - KCACHE);
}